// Round 7
// baseline (769.984 us; speedup 1.0000x reference)
//
#include <hip/hip_runtime.h>

#define N_NODES 100000
#define N_EDGES 1200000
#define GRAPHS 128
#define EPSBN 1e-5f
#define CAP 64      // per-node bucket capacity; P(in-deg >= 64) ~ 1e-30 for Poisson(12)
#define HG_G 32     // histogram blocks per segment
#define HG_SEG 4    // segments of 25000 bins (100 KB LDS each)
#define HG_BINS 25000

// ---------------- bucketed CSR build: ONE atomic per edge ----------------

__global__ __launch_bounds__(256) void k_build(const int* __restrict__ src,
                                               const int* __restrict__ dst,
                                               int* __restrict__ cnt,
                                               int* __restrict__ ecsr) {
    int e = blockIdx.x * 256 + threadIdx.x;
    if (e < N_EDGES) {
        int s = src[e], d = dst[e];
        int p = atomicAdd(&cnt[d], 1);
        ecsr[(d << 6) + p] = s;
    }
}

// ---------------- out-degree histogram: LDS-privatized, no global atomics ----------------

__global__ __launch_bounds__(256) void k_hist(const int* __restrict__ src,
                                              int* __restrict__ pdeg) {
    __shared__ int bins[HG_BINS];
    int t = threadIdx.x;
    int seg = blockIdx.x / HG_G, g = blockIdx.x % HG_G;
    for (int i = t; i < HG_BINS; i += 256) bins[i] = 0;
    __syncthreads();
    int lo = seg * HG_BINS, hi = lo + HG_BINS;
    const int chunk = N_EDGES / HG_G;   // 37500 exact
    int e0 = g * chunk, e1 = e0 + chunk;
    for (int e = e0 + t; e < e1; e += 256) {
        int s = src[e];
        if (s >= lo && s < hi) atomicAdd(&bins[s - lo], 1);
    }
    __syncthreads();
    for (int i = t; i < HG_BINS; i += 256)
        pdeg[(seg * HG_G + g) * HG_BINS + i] = bins[i];
}

__global__ __launch_bounds__(256) void k_degsum(const int* __restrict__ pdeg,
                                                float* __restrict__ dis) {
    int i = blockIdx.x * 256 + threadIdx.x;
    if (i >= N_NODES) return;
    int seg = i / HG_BINS, loc = i - seg * HG_BINS;
    int s = 0;
#pragma unroll
    for (int g = 0; g < HG_G; g++) s += pdeg[(seg * HG_G + g) * HG_BINS + loc];
    dis[i] = rsqrtf((float)s + 1.0f);   // +1 self-loop
}

// ---------------- BN stats over x: float4 loads, LDS reduce ----------------

__global__ __launch_bounds__(256) void k_stats(const float* __restrict__ x,
                                               float* __restrict__ sums) {
    const float4* x4 = (const float4*)x;
    int t = threadIdx.x;
    int q = t & 15, rg = t >> 4;
    float4 s = {0.f, 0.f, 0.f, 0.f}, s2 = {0.f, 0.f, 0.f, 0.f};
    for (int r = blockIdx.x * 16 + rg; r < N_NODES; r += gridDim.x * 16) {
        float4 v = x4[r * 16 + q];
        s.x += v.x; s.y += v.y; s.z += v.z; s.w += v.w;
        s2.x += v.x * v.x; s2.y += v.y * v.y; s2.z += v.z * v.z; s2.w += v.w * v.w;
    }
    __shared__ float red[2][16][64];
    red[0][rg][q * 4 + 0] = s.x;  red[0][rg][q * 4 + 1] = s.y;
    red[0][rg][q * 4 + 2] = s.z;  red[0][rg][q * 4 + 3] = s.w;
    red[1][rg][q * 4 + 0] = s2.x; red[1][rg][q * 4 + 1] = s2.y;
    red[1][rg][q * 4 + 2] = s2.z; red[1][rg][q * 4 + 3] = s2.w;
    __syncthreads();
    if (t < 64) {
        float a = 0.f, b = 0.f;
#pragma unroll
        for (int k = 0; k < 16; k++) { a += red[0][k][t]; b += red[1][k][t]; }
        atomicAdd(&sums[t], a);
        atomicAdd(&sums[64 + t], b);
    }
}

// ---------------- fold BN into GEMM: W' = diag(a)W, b' = c@W (+bias) ----------------

__global__ __launch_bounds__(256) void k_fold(const float* __restrict__ sums, const float* __restrict__ g,
                       const float* __restrict__ b, const float* __restrict__ W,
                       const float* __restrict__ bias_in, int has_bias,
                       float* __restrict__ Wout, float* __restrict__ bout) {
    __shared__ float a[64], cc[64];
    int t = threadIdx.x;
    if (t < 64) {
        float mu = sums[t] * (1.0f / N_NODES);
        float var = sums[64 + t] * (1.0f / N_NODES) - mu * mu;
        float av = g[t] * rsqrtf(var + EPSBN);
        a[t] = av;
        cc[t] = b[t] - mu * av;
    }
    __syncthreads();
    for (int i = t; i < 4096; i += 256) Wout[i] = a[i >> 6] * W[i];
    if (t < 64) {
        float acc = has_bias ? bias_in[t] : 0.0f;
        for (int k = 0; k < 64; k++) acc += cc[k] * W[k * 64 + t];
        bout[t] = acc;
    }
}

// ---------------- GEMM: Y[N,64] = X@W + bias, opt relu, opt per-row scale, opt stats ----------------

__global__ __launch_bounds__(256) void k_gemm2(const float* __restrict__ X, const float* __restrict__ W,
                        const float* __restrict__ bias, float* __restrict__ Y,
                        int relu, const float* __restrict__ scale,
                        float* __restrict__ sums, int do_stats) {
    int t = threadIdx.x;
    int j = t & 63;
    int rg = t >> 6;
    float wreg[64];
#pragma unroll
    for (int c = 0; c < 64; c++) wreg[c] = W[c * 64 + j];
    float bj = bias[j];
    __shared__ float xs[16][64];
    float s_sum = 0.f, s_sq = 0.f;
    for (int base = blockIdx.x * 16; base < N_NODES; base += gridDim.x * 16) {
        __syncthreads();
        ((float4*)xs)[t] = ((const float4*)(X + base * 64))[t];
        __syncthreads();
        int r0 = rg * 4;
        float a0 = bj, a1 = bj, a2 = bj, a3 = bj;
#pragma unroll
        for (int c = 0; c < 64; c++) {
            float w = wreg[c];
            a0 += xs[r0 + 0][c] * w;
            a1 += xs[r0 + 1][c] * w;
            a2 += xs[r0 + 2][c] * w;
            a3 += xs[r0 + 3][c] * w;
        }
        if (relu) {
            a0 = fmaxf(a0, 0.f); a1 = fmaxf(a1, 0.f);
            a2 = fmaxf(a2, 0.f); a3 = fmaxf(a3, 0.f);
        }
        if (scale) {   // fold dis[row] into output: hws = dis * (BN(h) @ W)
            a0 *= scale[base + r0 + 0];
            a1 *= scale[base + r0 + 1];
            a2 *= scale[base + r0 + 2];
            a3 *= scale[base + r0 + 3];
        }
        Y[(base + r0 + 0) * 64 + j] = a0;
        Y[(base + r0 + 1) * 64 + j] = a1;
        Y[(base + r0 + 2) * 64 + j] = a2;
        Y[(base + r0 + 3) * 64 + j] = a3;
        if (do_stats) {
            s_sum += a0 + a1 + a2 + a3;
            s_sq += a0 * a0 + a1 * a1 + a2 * a2 + a3 * a3;
        }
    }
    if (do_stats) {
        __syncthreads();
        xs[rg][j] = s_sum;
        xs[4 + rg][j] = s_sq;
        __syncthreads();
        if (t < 64) {
            atomicAdd(&sums[t], xs[0][t] + xs[1][t] + xs[2][t] + xs[3][t]);
            atomicAdd(&sums[64 + t], xs[4][t] + xs[5][t] + xs[6][t] + xs[7][t]);
        }
    }
}

// ---------------- fused aggregation: pure row-gather (weights pre-folded into hws) ----------------
// h[d] = relu( dis[d] * ( sum_e hws[s_e] + hws[d] ) + bias ), hws = dis * hw

__global__ __launch_bounds__(256) void k_agg(const float* __restrict__ hws, const float* __restrict__ dis,
                      const int* __restrict__ cnt, const int* __restrict__ ecsr,
                      const float* __restrict__ bias, float* __restrict__ hout,
                      float* __restrict__ sums, int do_stats) {
    const float4* hw4 = (const float4*)hws;
    int lane = threadIdx.x & 63;
    int wid = threadIdx.x >> 6;
    int g = lane >> 4, q = lane & 15;
    float4 bias4 = ((const float4*)bias)[q];
    float4 ssum = {0.f, 0.f, 0.f, 0.f}, ssq = {0.f, 0.f, 0.f, 0.f};
    for (int node = blockIdx.x * 4 + wid; node < N_NODES; node += gridDim.x * 4) {
        int m = cnt[node];
        int sL = 0;
        if (lane < m) sL = ecsr[(node << 6) + lane];
        float4 acc = {0.f, 0.f, 0.f, 0.f};
        if (g == 0) acc = hw4[node * 16 + q];   // self-loop term hws[d]
        int kmax = (m + 3) >> 2;
        for (int k = 0; k < kmax; k++) {
            int srcLane = 4 * k + g;
            int sE = __shfl(sL, srcLane, 64);
            if (srcLane < m) {
                float4 hv = hw4[sE * 16 + q];
                acc.x += hv.x; acc.y += hv.y; acc.z += hv.z; acc.w += hv.w;
            }
        }
        acc.x += __shfl_xor(acc.x, 16, 64); acc.y += __shfl_xor(acc.y, 16, 64);
        acc.z += __shfl_xor(acc.z, 16, 64); acc.w += __shfl_xor(acc.w, 16, 64);
        acc.x += __shfl_xor(acc.x, 32, 64); acc.y += __shfl_xor(acc.y, 32, 64);
        acc.z += __shfl_xor(acc.z, 32, 64); acc.w += __shfl_xor(acc.w, 32, 64);
        if (g == 0) {
            float dd = dis[node];
            float4 h;
            h.x = fmaxf(dd * acc.x + bias4.x, 0.f);
            h.y = fmaxf(dd * acc.y + bias4.y, 0.f);
            h.z = fmaxf(dd * acc.z + bias4.z, 0.f);
            h.w = fmaxf(dd * acc.w + bias4.w, 0.f);
            ((float4*)hout)[node * 16 + q] = h;
            if (do_stats) {
                ssum.x += h.x; ssum.y += h.y; ssum.z += h.z; ssum.w += h.w;
                ssq.x += h.x * h.x; ssq.y += h.y * h.y;
                ssq.z += h.z * h.z; ssq.w += h.w * h.w;
            }
        }
    }
    if (do_stats) {
        __shared__ float red[2][4][64];
        if (g == 0) {
            red[0][wid][q * 4 + 0] = ssum.x; red[0][wid][q * 4 + 1] = ssum.y;
            red[0][wid][q * 4 + 2] = ssum.z; red[0][wid][q * 4 + 3] = ssum.w;
            red[1][wid][q * 4 + 0] = ssq.x;  red[1][wid][q * 4 + 1] = ssq.y;
            red[1][wid][q * 4 + 2] = ssq.z;  red[1][wid][q * 4 + 3] = ssq.w;
        }
        __syncthreads();
        int t = threadIdx.x;
        if (t < 64) {
            atomicAdd(&sums[t], red[0][0][t] + red[0][1][t] + red[0][2][t] + red[0][3][t]);
            atomicAdd(&sums[64 + t], red[1][0][t] + red[1][1][t] + red[1][2][t] + red[1][3][t]);
        }
    }
}

// ---------------- global_add_pool + fused BN-fc stats ----------------

__global__ __launch_bounds__(256) void k_pool(const float* __restrict__ h, const int* __restrict__ batch,
                       float* __restrict__ hg, float* __restrict__ sums) {
    int g = blockIdx.x;
    int lo = 0, hi = N_NODES;
    while (lo < hi) { int m = (lo + hi) >> 1; if (batch[m] < g) lo = m + 1; else hi = m; }
    int start = lo;
    lo = start; hi = N_NODES;
    while (lo < hi) { int m = (lo + hi) >> 1; if (batch[m] < g + 1) lo = m + 1; else hi = m; }
    int end = lo;
    int c = threadIdx.x & 63, rg = threadIdx.x >> 6;
    float s = 0.f;
    for (int r = start + rg; r < end; r += 4) s += h[r * 64 + c];
    __shared__ float ls[4][64];
    ls[rg][c] = s;
    __syncthreads();
    if (rg == 0) {
        float v = ls[0][c] + ls[1][c] + ls[2][c] + ls[3][c];
        hg[g * 64 + c] = v;
        atomicAdd(&sums[c], v);
        atomicAdd(&sums[64 + c], v * v);
    }
}

// ---------------- tail: BN -> FC+relu -> BN -> classifier -> log_softmax ----------------

__global__ __launch_bounds__(512) void k_tail(const float* __restrict__ hg_in, const float* __restrict__ sums,
                       const float* __restrict__ g1, const float* __restrict__ b1,
                       const float* __restrict__ Wfc, const float* __restrict__ bfc,
                       const float* __restrict__ g2, const float* __restrict__ b2,
                       const float* __restrict__ Wcls, const float* __restrict__ bcls,
                       float* __restrict__ out) {
    __shared__ float hgn[8192];
    __shared__ float h2[8192];
    __shared__ float red[2][8][64];
    __shared__ float a[64], cc[64];
    __shared__ float Wc[640];
    __shared__ float logits[1280];
    __shared__ float lse[128];
    int t = threadIdx.x;
    int j = t & 63;
    int w = t >> 6;

    if (t < 64) {
        float mu = sums[t] * (1.f / 128.f);
        float var = sums[64 + t] * (1.f / 128.f) - mu * mu;
        float av = g1[t] * rsqrtf(var + EPSBN);
        a[t] = av; cc[t] = b1[t] - mu * av;
    }
    for (int i = t; i < 640; i += 512) Wc[i] = Wcls[i];
    __syncthreads();
    for (int i = t; i < 8192; i += 512) hgn[i] = hg_in[i] * a[i & 63] + cc[i & 63];

    float wreg[64];
#pragma unroll
    for (int q = 0; q < 64; q++) wreg[q] = Wfc[q * 64 + j];
    float bj = bfc[j];
    __syncthreads();

    float acc[16];
#pragma unroll
    for (int r = 0; r < 16; r++) acc[r] = bj;
    const float4* hgn4 = (const float4*)hgn;
#pragma unroll
    for (int q4 = 0; q4 < 16; q4++) {
#pragma unroll
        for (int r = 0; r < 16; r++) {
            float4 hv = hgn4[(w * 16 + r) * 16 + q4];
            acc[r] += hv.x * wreg[q4 * 4 + 0] + hv.y * wreg[q4 * 4 + 1]
                    + hv.z * wreg[q4 * 4 + 2] + hv.w * wreg[q4 * 4 + 3];
        }
    }
    float s = 0.f, s2 = 0.f;
#pragma unroll
    for (int r = 0; r < 16; r++) {
        float v = fmaxf(acc[r], 0.f);
        h2[(w * 16 + r) * 64 + j] = v;
        s += v; s2 += v * v;
    }
    red[0][w][j] = s; red[1][w][j] = s2;
    __syncthreads();

    if (t < 64) {
        float su = 0.f, sq = 0.f;
#pragma unroll
        for (int k = 0; k < 8; k++) { su += red[0][k][t]; sq += red[1][k][t]; }
        float mu = su * (1.f / 128.f);
        float var = sq * (1.f / 128.f) - mu * mu;
        float av = g2[t] * rsqrtf(var + EPSBN);
        a[t] = av; cc[t] = b2[t] - mu * av;
    }
    __syncthreads();
    for (int i = t; i < 8192; i += 512) h2[i] = h2[i] * a[i & 63] + cc[i & 63];
    __syncthreads();

    for (int idx = t; idx < 1280; idx += 512) {
        int row = idx / 10, o = idx - row * 10;
        float v = bcls[o];
#pragma unroll
        for (int q = 0; q < 64; q++) v += h2[row * 64 + q] * Wc[q * 10 + o];
        logits[idx] = v;
    }
    __syncthreads();
    if (t < 128) {
        float mx = -1e30f;
#pragma unroll
        for (int o = 0; o < 10; o++) mx = fmaxf(mx, logits[t * 10 + o]);
        float se = 0.f;
#pragma unroll
        for (int o = 0; o < 10; o++) se += expf(logits[t * 10 + o] - mx);
        lse[t] = mx + logf(se);
    }
    __syncthreads();
    for (int idx = t; idx < 1280; idx += 512) out[idx] = logits[idx] - lse[idx / 10];
}

// ---------------- launcher ----------------

extern "C" void kernel_launch(void* const* d_in, const int* in_sizes, int n_in,
                              void* d_out, int out_size, void* d_ws, size_t ws_size,
                              hipStream_t stream) {
    const float* x         = (const float*)d_in[0];
    const int*   ei        = (const int*)  d_in[1];
    const int*   batch     = (const int*)  d_in[2];
    const float* bn_feat_g = (const float*)d_in[3];
    const float* bn_feat_b = (const float*)d_in[4];
    const float* W_feat    = (const float*)d_in[5];
    const float* b_feat    = (const float*)d_in[6];
    const float* conv_bn_g = (const float*)d_in[7];
    const float* conv_bn_b = (const float*)d_in[8];
    const float* conv_W    = (const float*)d_in[9];
    const float* conv_b    = (const float*)d_in[10];
    const float* bn_fc_g   = (const float*)d_in[11];
    const float* bn_fc_b   = (const float*)d_in[12];
    const float* W_fc      = (const float*)d_in[13];
    const float* b_fc      = (const float*)d_in[14];
    const float* bn_hid_g  = (const float*)d_in[15];
    const float* bn_hid_b  = (const float*)d_in[16];
    const float* W_cls     = (const float*)d_in[17];
    const float* b_cls     = (const float*)d_in[18];
    float* out = (float*)d_out;

    float* ws   = (float*)d_ws;
    float* hbuf = ws;                         // 6,400,000 f
    float* hws  = ws + 6400000;               // 6,400,000 f (scaled GEMM out; aliased by pdeg early)
    float* dis  = ws + 12800000;              // 100,000 f
    float* Wt   = ws + 12900000;              // 4096 f
    float* bt   = Wt + 4096;                  // 64 f
    float* hg   = bt + 64;                    // 8192 f
    float* sums = hg + 8192;                  // 640 f  (sx, s0, s1, s2, s3)
    int*   cnt  = (int*)(sums + 640);         // 100,000 i
    int*   ecsr = cnt + 100000;               // 6,400,000 i (100k * CAP)
    int*   pdeg = (int*)hws;                  // 3,200,000 i scratch, dead before hws is written

    float* sx = sums;
    float* s0 = sums + 128;
    float* s1 = sums + 256;
    float* s2 = sums + 384;
    float* s3 = sums + 512;

    const int* srcp = ei;
    const int* dstp = ei + N_EDGES;

    // zero sums + cnt in one contiguous memset
    hipMemsetAsync(sums, 0, (640 + 100000) * sizeof(float), stream);

    // CSR build (1 atomic/edge) + LDS-privatized out-degree histogram -> dis
    k_build<<<(N_EDGES + 255) / 256, 256, 0, stream>>>(srcp, dstp, cnt, ecsr);
    k_hist<<<HG_SEG * HG_G, 256, 0, stream>>>(srcp, pdeg);
    k_degsum<<<(N_NODES + 255) / 256, 256, 0, stream>>>(pdeg, dis);

    // feature layer: BN (stats on x) folded into linear, relu, fused stats for conv_bn[0]
    k_stats<<<512, 256, 0, stream>>>(x, sx);
    k_fold<<<1, 256, 0, stream>>>(sx, bn_feat_g, bn_feat_b, W_feat, b_feat, 1, Wt, bt);
    k_gemm2<<<2048, 256, 0, stream>>>(x, Wt, bt, hbuf, 1, nullptr, s0, 1);

    // 3 GCN conv layers
    const float* lsums[3] = { s0, s1, s2 };
    for (int l = 0; l < 3; l++) {
        k_fold<<<1, 256, 0, stream>>>(lsums[l], conv_bn_g + l * 64, conv_bn_b + l * 64,
                                      conv_W + l * 4096, nullptr, 0, Wt, bt);
        k_gemm2<<<2048, 256, 0, stream>>>(hbuf, Wt, bt, hws, 0, dis, nullptr, 0);
        k_agg<<<2048, 256, 0, stream>>>(hws, dis, cnt, ecsr, conv_b + l * 64, hbuf,
                                        (float*)lsums[(l + 1 < 3) ? l + 1 : 0], l < 2 ? 1 : 0);
    }

    // pooling (+ BN-fc stats) + tail
    k_pool<<<GRAPHS, 256, 0, stream>>>(hbuf, batch, hg, s3);
    k_tail<<<1, 512, 0, stream>>>(hg, s3, bn_fc_g, bn_fc_b, W_fc, b_fc,
                                  bn_hid_g, bn_hid_b, W_cls, b_cls, out);
}

// Round 8
// 722.351 us; speedup vs baseline: 1.0659x; 1.0659x over previous
//
#include <hip/hip_runtime.h>
#include <hip/hip_fp16.h>

#define N_NODES 100000
#define N_EDGES 1200000
#define GRAPHS 128
#define EPSBN 1e-5f
#define CAP 64      // per-node bucket capacity; P(in-deg >= 64) ~ 1e-30 for Poisson(12)
#define HG_G 32     // histogram blocks per segment
#define HG_SEG 4    // segments of 25000 bins (100 KB LDS each)
#define HG_BINS 25000

// ---------------- bucketed CSR build: ONE atomic per edge ----------------

__global__ __launch_bounds__(256) void k_build(const int* __restrict__ src,
                                               const int* __restrict__ dst,
                                               int* __restrict__ cnt,
                                               int* __restrict__ ecsr) {
    int e = blockIdx.x * 256 + threadIdx.x;
    if (e < N_EDGES) {
        int s = src[e], d = dst[e];
        int p = atomicAdd(&cnt[d], 1);
        ecsr[(d << 6) + p] = s;
    }
}

// ---------------- out-degree histogram: LDS-privatized, no global atomics ----------------

__global__ __launch_bounds__(256) void k_hist(const int* __restrict__ src,
                                              int* __restrict__ pdeg) {
    __shared__ int bins[HG_BINS];
    int t = threadIdx.x;
    int seg = blockIdx.x / HG_G, g = blockIdx.x % HG_G;
    for (int i = t; i < HG_BINS; i += 256) bins[i] = 0;
    __syncthreads();
    int lo = seg * HG_BINS, hi = lo + HG_BINS;
    const int chunk = N_EDGES / HG_G;   // 37500 exact
    int e0 = g * chunk, e1 = e0 + chunk;
    for (int e = e0 + t; e < e1; e += 256) {
        int s = src[e];
        if (s >= lo && s < hi) atomicAdd(&bins[s - lo], 1);
    }
    __syncthreads();
    for (int i = t; i < HG_BINS; i += 256)
        pdeg[(seg * HG_G + g) * HG_BINS + i] = bins[i];
}

__global__ __launch_bounds__(256) void k_degsum(const int* __restrict__ pdeg,
                                                float* __restrict__ dis) {
    int i = blockIdx.x * 256 + threadIdx.x;
    if (i >= N_NODES) return;
    int seg = i / HG_BINS, loc = i - seg * HG_BINS;
    int s = 0;
#pragma unroll
    for (int g = 0; g < HG_G; g++) s += pdeg[(seg * HG_G + g) * HG_BINS + loc];
    dis[i] = rsqrtf((float)s + 1.0f);   // +1 self-loop
}

// ---------------- BN stats over x: float4 loads, LDS reduce ----------------

__global__ __launch_bounds__(256) void k_stats(const float* __restrict__ x,
                                               float* __restrict__ sums) {
    const float4* x4 = (const float4*)x;
    int t = threadIdx.x;
    int q = t & 15, rg = t >> 4;
    float4 s = {0.f, 0.f, 0.f, 0.f}, s2 = {0.f, 0.f, 0.f, 0.f};
    for (int r = blockIdx.x * 16 + rg; r < N_NODES; r += gridDim.x * 16) {
        float4 v = x4[r * 16 + q];
        s.x += v.x; s.y += v.y; s.z += v.z; s.w += v.w;
        s2.x += v.x * v.x; s2.y += v.y * v.y; s2.z += v.z * v.z; s2.w += v.w * v.w;
    }
    __shared__ float red[2][16][64];
    red[0][rg][q * 4 + 0] = s.x;  red[0][rg][q * 4 + 1] = s.y;
    red[0][rg][q * 4 + 2] = s.z;  red[0][rg][q * 4 + 3] = s.w;
    red[1][rg][q * 4 + 0] = s2.x; red[1][rg][q * 4 + 1] = s2.y;
    red[1][rg][q * 4 + 2] = s2.z; red[1][rg][q * 4 + 3] = s2.w;
    __syncthreads();
    if (t < 64) {
        float a = 0.f, b = 0.f;
#pragma unroll
        for (int k = 0; k < 16; k++) { a += red[0][k][t]; b += red[1][k][t]; }
        atomicAdd(&sums[t], a);
        atomicAdd(&sums[64 + t], b);
    }
}

// ---------------- fold BN into GEMM: W' = diag(a)W, b' = c@W (+bias) ----------------

__global__ __launch_bounds__(256) void k_fold(const float* __restrict__ sums, const float* __restrict__ g,
                       const float* __restrict__ b, const float* __restrict__ W,
                       const float* __restrict__ bias_in, int has_bias,
                       float* __restrict__ Wout, float* __restrict__ bout) {
    __shared__ float a[64], cc[64];
    int t = threadIdx.x;
    if (t < 64) {
        float mu = sums[t] * (1.0f / N_NODES);
        float var = sums[64 + t] * (1.0f / N_NODES) - mu * mu;
        float av = g[t] * rsqrtf(var + EPSBN);
        a[t] = av;
        cc[t] = b[t] - mu * av;
    }
    __syncthreads();
    for (int i = t; i < 4096; i += 256) Wout[i] = a[i >> 6] * W[i];
    if (t < 64) {
        float acc = has_bias ? bias_in[t] : 0.0f;
        for (int k = 0; k < 64; k++) acc += cc[k] * W[k * 64 + t];
        bout[t] = acc;
    }
}

// ---------------- GEMM: Y = X@W + bias; f32 out (Y) or scaled f16 out (Yh) ----------------

__global__ __launch_bounds__(256) void k_gemm2(const float* __restrict__ X, const float* __restrict__ W,
                        const float* __restrict__ bias, float* __restrict__ Y,
                        __half* __restrict__ Yh,
                        int relu, const float* __restrict__ scale,
                        float* __restrict__ sums, int do_stats) {
    int t = threadIdx.x;
    int j = t & 63;
    int rg = t >> 6;
    float wreg[64];
#pragma unroll
    for (int c = 0; c < 64; c++) wreg[c] = W[c * 64 + j];
    float bj = bias[j];
    __shared__ float xs[16][64];
    float s_sum = 0.f, s_sq = 0.f;
    for (int base = blockIdx.x * 16; base < N_NODES; base += gridDim.x * 16) {
        __syncthreads();
        ((float4*)xs)[t] = ((const float4*)(X + base * 64))[t];
        __syncthreads();
        int r0 = rg * 4;
        float a0 = bj, a1 = bj, a2 = bj, a3 = bj;
#pragma unroll
        for (int c = 0; c < 64; c++) {
            float w = wreg[c];
            a0 += xs[r0 + 0][c] * w;
            a1 += xs[r0 + 1][c] * w;
            a2 += xs[r0 + 2][c] * w;
            a3 += xs[r0 + 3][c] * w;
        }
        if (relu) {
            a0 = fmaxf(a0, 0.f); a1 = fmaxf(a1, 0.f);
            a2 = fmaxf(a2, 0.f); a3 = fmaxf(a3, 0.f);
        }
        if (scale) {   // hws = dis[row] * (BN(h) @ W)
            a0 *= scale[base + r0 + 0];
            a1 *= scale[base + r0 + 1];
            a2 *= scale[base + r0 + 2];
            a3 *= scale[base + r0 + 3];
        }
        if (Yh) {
            Yh[(base + r0 + 0) * 64 + j] = __float2half_rn(a0);
            Yh[(base + r0 + 1) * 64 + j] = __float2half_rn(a1);
            Yh[(base + r0 + 2) * 64 + j] = __float2half_rn(a2);
            Yh[(base + r0 + 3) * 64 + j] = __float2half_rn(a3);
        } else {
            Y[(base + r0 + 0) * 64 + j] = a0;
            Y[(base + r0 + 1) * 64 + j] = a1;
            Y[(base + r0 + 2) * 64 + j] = a2;
            Y[(base + r0 + 3) * 64 + j] = a3;
        }
        if (do_stats) {
            s_sum += a0 + a1 + a2 + a3;
            s_sq += a0 * a0 + a1 * a1 + a2 * a2 + a3 * a3;
        }
    }
    if (do_stats) {
        __syncthreads();
        xs[rg][j] = s_sum;
        xs[4 + rg][j] = s_sq;
        __syncthreads();
        if (t < 64) {
            atomicAdd(&sums[t], xs[0][t] + xs[1][t] + xs[2][t] + xs[3][t]);
            atomicAdd(&sums[64 + t], xs[4][t] + xs[5][t] + xs[6][t] + xs[7][t]);
        }
    }
}

// ---------------- fused aggregation: fp16 row-gathers, branch-free bulk loop ----------------
// h[d] = relu( dis[d] * ( sum_e hws[s_e] + hws[d] ) + bias ),   hws = dis * hw (fp16)

__global__ __launch_bounds__(256) void k_agg(const __half* __restrict__ hws, const float* __restrict__ dis,
                      const int* __restrict__ cnt, const int* __restrict__ ecsr,
                      const float* __restrict__ bias, float* __restrict__ hout,
                      float* __restrict__ sums, int do_stats) {
    const float2* hw2 = (const float2*)hws;   // 8B = 4 halves per lane-quad
    int lane = threadIdx.x & 63;
    int wid = threadIdx.x >> 6;
    int g = lane >> 4, q = lane & 15;
    float4 bias4 = ((const float4*)bias)[q];
    float4 ssum = {0.f, 0.f, 0.f, 0.f}, ssq = {0.f, 0.f, 0.f, 0.f};
    for (int node = blockIdx.x * 4 + wid; node < N_NODES; node += gridDim.x * 4) {
        int m = cnt[node];
        int sL = 0;
        if (lane < m) sL = ecsr[(node << 6) + lane];
        float4 acc = {0.f, 0.f, 0.f, 0.f};
        if (g == 0) {   // self-loop term hws[d]
            float2 raw = hw2[node * 16 + q];
            __half2* hp = (__half2*)&raw;
            float2 lo = __half22float2(hp[0]), hi = __half22float2(hp[1]);
            acc.x = lo.x; acc.y = lo.y; acc.z = hi.x; acc.w = hi.y;
        }
        int kfull = m >> 2;
        for (int k = 0; k < kfull; k++) {       // branch-free bulk: unconditional loads
            int sE = __shfl(sL, 4 * k + g, 64);
            float2 raw = hw2[sE * 16 + q];
            __half2* hp = (__half2*)&raw;
            float2 lo = __half22float2(hp[0]), hi = __half22float2(hp[1]);
            acc.x += lo.x; acc.y += lo.y; acc.z += hi.x; acc.w += hi.y;
        }
        int rem = m & 3;
        if (rem) {                               // predicated remainder
            int sE = __shfl(sL, 4 * kfull + g, 64);
            float wE = (g < rem) ? 1.0f : 0.0f;
            float2 raw = hw2[sE * 16 + q];
            __half2* hp = (__half2*)&raw;
            float2 lo = __half22float2(hp[0]), hi = __half22float2(hp[1]);
            acc.x += wE * lo.x; acc.y += wE * lo.y;
            acc.z += wE * hi.x; acc.w += wE * hi.y;
        }
        acc.x += __shfl_xor(acc.x, 16, 64); acc.y += __shfl_xor(acc.y, 16, 64);
        acc.z += __shfl_xor(acc.z, 16, 64); acc.w += __shfl_xor(acc.w, 16, 64);
        acc.x += __shfl_xor(acc.x, 32, 64); acc.y += __shfl_xor(acc.y, 32, 64);
        acc.z += __shfl_xor(acc.z, 32, 64); acc.w += __shfl_xor(acc.w, 32, 64);
        if (g == 0) {
            float dd = dis[node];
            float4 h;
            h.x = fmaxf(dd * acc.x + bias4.x, 0.f);
            h.y = fmaxf(dd * acc.y + bias4.y, 0.f);
            h.z = fmaxf(dd * acc.z + bias4.z, 0.f);
            h.w = fmaxf(dd * acc.w + bias4.w, 0.f);
            ((float4*)hout)[node * 16 + q] = h;
            if (do_stats) {
                ssum.x += h.x; ssum.y += h.y; ssum.z += h.z; ssum.w += h.w;
                ssq.x += h.x * h.x; ssq.y += h.y * h.y;
                ssq.z += h.z * h.z; ssq.w += h.w * h.w;
            }
        }
    }
    if (do_stats) {
        __shared__ float red[2][4][64];
        if (g == 0) {
            red[0][wid][q * 4 + 0] = ssum.x; red[0][wid][q * 4 + 1] = ssum.y;
            red[0][wid][q * 4 + 2] = ssum.z; red[0][wid][q * 4 + 3] = ssum.w;
            red[1][wid][q * 4 + 0] = ssq.x;  red[1][wid][q * 4 + 1] = ssq.y;
            red[1][wid][q * 4 + 2] = ssq.z;  red[1][wid][q * 4 + 3] = ssq.w;
        }
        __syncthreads();
        int t = threadIdx.x;
        if (t < 64) {
            atomicAdd(&sums[t], red[0][0][t] + red[0][1][t] + red[0][2][t] + red[0][3][t]);
            atomicAdd(&sums[64 + t], red[1][0][t] + red[1][1][t] + red[1][2][t] + red[1][3][t]);
        }
    }
}

// ---------------- global_add_pool + fused BN-fc stats ----------------

__global__ __launch_bounds__(256) void k_pool(const float* __restrict__ h, const int* __restrict__ batch,
                       float* __restrict__ hg, float* __restrict__ sums) {
    int g = blockIdx.x;
    int lo = 0, hi = N_NODES;
    while (lo < hi) { int m = (lo + hi) >> 1; if (batch[m] < g) lo = m + 1; else hi = m; }
    int start = lo;
    lo = start; hi = N_NODES;
    while (lo < hi) { int m = (lo + hi) >> 1; if (batch[m] < g + 1) lo = m + 1; else hi = m; }
    int end = lo;
    int c = threadIdx.x & 63, rg = threadIdx.x >> 6;
    float s = 0.f;
    for (int r = start + rg; r < end; r += 4) s += h[r * 64 + c];
    __shared__ float ls[4][64];
    ls[rg][c] = s;
    __syncthreads();
    if (rg == 0) {
        float v = ls[0][c] + ls[1][c] + ls[2][c] + ls[3][c];
        hg[g * 64 + c] = v;
        atomicAdd(&sums[c], v);
        atomicAdd(&sums[64 + c], v * v);
    }
}

// ---------------- tail: BN -> FC+relu -> BN -> classifier -> log_softmax ----------------

__global__ __launch_bounds__(512) void k_tail(const float* __restrict__ hg_in, const float* __restrict__ sums,
                       const float* __restrict__ g1, const float* __restrict__ b1,
                       const float* __restrict__ Wfc, const float* __restrict__ bfc,
                       const float* __restrict__ g2, const float* __restrict__ b2,
                       const float* __restrict__ Wcls, const float* __restrict__ bcls,
                       float* __restrict__ out) {
    __shared__ float hgn[8192];
    __shared__ float h2[8192];
    __shared__ float red[2][8][64];
    __shared__ float a[64], cc[64];
    __shared__ float Wc[640];
    __shared__ float logits[1280];
    __shared__ float lse[128];
    int t = threadIdx.x;
    int j = t & 63;
    int w = t >> 6;

    if (t < 64) {
        float mu = sums[t] * (1.f / 128.f);
        float var = sums[64 + t] * (1.f / 128.f) - mu * mu;
        float av = g1[t] * rsqrtf(var + EPSBN);
        a[t] = av; cc[t] = b1[t] - mu * av;
    }
    for (int i = t; i < 640; i += 512) Wc[i] = Wcls[i];
    __syncthreads();
    for (int i = t; i < 8192; i += 512) hgn[i] = hg_in[i] * a[i & 63] + cc[i & 63];

    float wreg[64];
#pragma unroll
    for (int q = 0; q < 64; q++) wreg[q] = Wfc[q * 64 + j];
    float bj = bfc[j];
    __syncthreads();

    float acc[16];
#pragma unroll
    for (int r = 0; r < 16; r++) acc[r] = bj;
    const float4* hgn4 = (const float4*)hgn;
#pragma unroll
    for (int q4 = 0; q4 < 16; q4++) {
#pragma unroll
        for (int r = 0; r < 16; r++) {
            float4 hv = hgn4[(w * 16 + r) * 16 + q4];
            acc[r] += hv.x * wreg[q4 * 4 + 0] + hv.y * wreg[q4 * 4 + 1]
                    + hv.z * wreg[q4 * 4 + 2] + hv.w * wreg[q4 * 4 + 3];
        }
    }
    float s = 0.f, s2 = 0.f;
#pragma unroll
    for (int r = 0; r < 16; r++) {
        float v = fmaxf(acc[r], 0.f);
        h2[(w * 16 + r) * 64 + j] = v;
        s += v; s2 += v * v;
    }
    red[0][w][j] = s; red[1][w][j] = s2;
    __syncthreads();

    if (t < 64) {
        float su = 0.f, sq = 0.f;
#pragma unroll
        for (int k = 0; k < 8; k++) { su += red[0][k][t]; sq += red[1][k][t]; }
        float mu = su * (1.f / 128.f);
        float var = sq * (1.f / 128.f) - mu * mu;
        float av = g2[t] * rsqrtf(var + EPSBN);
        a[t] = av; cc[t] = b2[t] - mu * av;
    }
    __syncthreads();
    for (int i = t; i < 8192; i += 512) h2[i] = h2[i] * a[i & 63] + cc[i & 63];
    __syncthreads();

    for (int idx = t; idx < 1280; idx += 512) {
        int row = idx / 10, o = idx - row * 10;
        float v = bcls[o];
#pragma unroll
        for (int q = 0; q < 64; q++) v += h2[row * 64 + q] * Wc[q * 10 + o];
        logits[idx] = v;
    }
    __syncthreads();
    if (t < 128) {
        float mx = -1e30f;
#pragma unroll
        for (int o = 0; o < 10; o++) mx = fmaxf(mx, logits[t * 10 + o]);
        float se = 0.f;
#pragma unroll
        for (int o = 0; o < 10; o++) se += expf(logits[t * 10 + o] - mx);
        lse[t] = mx + logf(se);
    }
    __syncthreads();
    for (int idx = t; idx < 1280; idx += 512) out[idx] = logits[idx] - lse[idx / 10];
}

// ---------------- launcher ----------------

extern "C" void kernel_launch(void* const* d_in, const int* in_sizes, int n_in,
                              void* d_out, int out_size, void* d_ws, size_t ws_size,
                              hipStream_t stream) {
    const float* x         = (const float*)d_in[0];
    const int*   ei        = (const int*)  d_in[1];
    const int*   batch     = (const int*)  d_in[2];
    const float* bn_feat_g = (const float*)d_in[3];
    const float* bn_feat_b = (const float*)d_in[4];
    const float* W_feat    = (const float*)d_in[5];
    const float* b_feat    = (const float*)d_in[6];
    const float* conv_bn_g = (const float*)d_in[7];
    const float* conv_bn_b = (const float*)d_in[8];
    const float* conv_W    = (const float*)d_in[9];
    const float* conv_b    = (const float*)d_in[10];
    const float* bn_fc_g   = (const float*)d_in[11];
    const float* bn_fc_b   = (const float*)d_in[12];
    const float* W_fc      = (const float*)d_in[13];
    const float* b_fc      = (const float*)d_in[14];
    const float* bn_hid_g  = (const float*)d_in[15];
    const float* bn_hid_b  = (const float*)d_in[16];
    const float* W_cls     = (const float*)d_in[17];
    const float* b_cls     = (const float*)d_in[18];
    float* out = (float*)d_out;

    float* ws   = (float*)d_ws;
    float* hbuf = ws;                         // 6,400,000 f
    __half* hws = (__half*)(ws + 6400000);    // 6,400,000 halves = 3,200,000 f-slots
    float* dis  = ws + 9600000;               // 100,000 f
    float* Wt   = ws + 9700000;               // 4096 f
    float* bt   = Wt + 4096;                  // 64 f
    float* hg   = bt + 64;                    // 8192 f
    float* sums = hg + 8192;                  // 640 f  (sx, s0, s1, s2, s3)
    int*   cnt  = (int*)(sums + 640);         // 100,000 i
    int*   ecsr = cnt + 100000;               // 6,400,000 i (100k * CAP)
    int*   pdeg = (int*)hws;                  // 3,200,000 i scratch; dead before hws written

    float* sx = sums;
    float* s0 = sums + 128;
    float* s1 = sums + 256;
    float* s2 = sums + 384;
    float* s3 = sums + 512;

    const int* srcp = ei;
    const int* dstp = ei + N_EDGES;

    // zero sums + cnt in one contiguous memset
    hipMemsetAsync(sums, 0, (640 + 100000) * sizeof(float), stream);

    // CSR build (1 atomic/edge) + LDS-privatized out-degree histogram -> dis
    k_build<<<(N_EDGES + 255) / 256, 256, 0, stream>>>(srcp, dstp, cnt, ecsr);
    k_hist<<<HG_SEG * HG_G, 256, 0, stream>>>(srcp, pdeg);
    k_degsum<<<(N_NODES + 255) / 256, 256, 0, stream>>>(pdeg, dis);

    // feature layer: BN (stats on x) folded into linear, relu, fused stats for conv_bn[0]
    k_stats<<<512, 256, 0, stream>>>(x, sx);
    k_fold<<<1, 256, 0, stream>>>(sx, bn_feat_g, bn_feat_b, W_feat, b_feat, 1, Wt, bt);
    k_gemm2<<<2048, 256, 0, stream>>>(x, Wt, bt, hbuf, nullptr, 1, nullptr, s0, 1);

    // 3 GCN conv layers
    const float* lsums[3] = { s0, s1, s2 };
    for (int l = 0; l < 3; l++) {
        k_fold<<<1, 256, 0, stream>>>(lsums[l], conv_bn_g + l * 64, conv_bn_b + l * 64,
                                      conv_W + l * 4096, nullptr, 0, Wt, bt);
        k_gemm2<<<2048, 256, 0, stream>>>(hbuf, Wt, bt, nullptr, hws, 0, dis, nullptr, 0);
        k_agg<<<2048, 256, 0, stream>>>(hws, dis, cnt, ecsr, conv_b + l * 64, hbuf,
                                        (float*)lsums[(l + 1 < 3) ? l + 1 : 0], l < 2 ? 1 : 0);
    }

    // pooling (+ BN-fc stats) + tail
    k_pool<<<GRAPHS, 256, 0, stream>>>(hbuf, batch, hg, s3);
    k_tail<<<1, 512, 0, stream>>>(hg, s3, bn_fc_g, bn_fc_b, W_fc, b_fc,
                                  bn_hid_g, bn_hid_b, W_cls, b_cls, out);
}